// Round 9
// baseline (56.011 us; speedup 1.0000x reference)
//
#include <hip/hip_runtime.h>
#include <hip/hip_bf16.h>

#define B_   64
#define N_   512
#define K_   16
#define D_   128

typedef float f32x4  __attribute__((ext_vector_type(4)));
typedef short bf16x8 __attribute__((ext_vector_type(8)));

static __device__ __forceinline__ short f2bf(float x) {
    union { float f; unsigned u; } v; v.f = x;
    unsigned r = v.u + 0x7fffu + ((v.u >> 16) & 1u);  // RNE
    return (short)(r >> 16);
}
static __device__ __forceinline__ float bfbits2f(unsigned hi_bits) {
    return __uint_as_float(hi_bits);
}
static __device__ __forceinline__ float bf2f(short h) {
    return __uint_as_float(((unsigned)(unsigned short)h) << 16);
}
// tanh(x) = 1 - 2/(e^{2x}+1); exact at +/-inf, ~1e-7 rel error
static __device__ __forceinline__ float fast_tanh(float x) {
    float e = __expf(2.f * x);
    return 1.f - 2.f * __builtin_amdgcn_rcpf(e + 1.f);
}

#define LDX 136   // 128 + 8 pad shorts

// ---------------------------------------------------------------------------
// pack: blocks 0..23  -> Bp1e (enc1), Bpw (weight), Bp2 (enc2), K=128 frag order
//       blocks 24..55 -> zero d_out
// frag elem j of lane l, tile nt, step ks = B[ks*32 + (l>>4)*8 + j][nt*16 + (l&15)]
// ---------------------------------------------------------------------------
__global__ __launch_bounds__(256) void pack(const float* __restrict__ enc1,
                                            const float* __restrict__ wgt,
                                            const float* __restrict__ enc2,
                                            short* __restrict__ Bp1e,
                                            short* __restrict__ Bpw,
                                            short* __restrict__ Bp2,
                                            float* __restrict__ out) {
    const int blk = blockIdx.x, t = threadIdx.x;
    if (blk >= 24) { out[(blk - 24) * 256 + t] = 0.f; return; }
    const int ptid = blk * 256 + t;          // 0..6143
    const int m3 = ptid >> 11;               // 0 enc1, 1 weight, 2 enc2
    const int r = ptid & 2047;
    const int ks = r >> 9, nt = (r >> 6) & 7, l = r & 63;
    const int k0 = ks * 32 + (l >> 4) * 8;
    const int col = nt * 16 + (l & 15);
    const float* src = (m3 == 0) ? enc1 : (m3 == 1) ? wgt : enc2;
    short* dst = (m3 == 0) ? Bp1e : (m3 == 1) ? Bpw : Bp2;
    short o8[8];
#pragma unroll
    for (int j = 0; j < 8; ++j) o8[j] = f2bf(src[(k0 + j) * 128 + col]);
    *(int4*)&dst[(size_t)r * 8] = *(int4*)o8;
}

// ---------------------------------------------------------------------------
// proj: dense Y = X @ W (bf16 out).  4096 blocks x 256 thr, 16 rows/block.
// XCD g handles batches [8g,8g+8) of BOTH matrices (word->wordp, lib->libp).
// ---------------------------------------------------------------------------
__global__ __launch_bounds__(256) void proj(const float* __restrict__ word,
                                            const float* __restrict__ lib,
                                            const short* __restrict__ Bp1e,
                                            const short* __restrict__ Bpw,
                                            short* __restrict__ wordp,
                                            short* __restrict__ libp) {
    __shared__ short sX[16 * LDX];
    const int hw = blockIdx.x, t = threadIdx.x;
    const int g = hw & 7, q = hw >> 3;
    const int m = q >> 8;                    // 0: word, 1: lib
    const int Lb = g * 256 + (q & 255);      // row-block 0..2047
    const float* X = m ? lib : word;
    const short* Bp = m ? Bpw : Bp1e;
    short* Y = m ? libp : wordp;
    const size_t rb = (size_t)Lb * 16;       // first row

    // stage 16x128 fp32 -> bf16 LDS
#pragma unroll
    for (int i = 0; i < 2; ++i) {
        const int gidx = i * 1024 + t * 4;
        const int row = gidx >> 7, col = gidx & 127;
        float4 v = *(const float4*)&X[rb * 128 + gidx];
        short4 s; s.x = f2bf(v.x); s.y = f2bf(v.y); s.z = f2bf(v.z); s.w = f2bf(v.w);
        *(short4*)&sX[row * LDX + col] = s;
    }
    __syncthreads();

    const int w = t >> 6, l = t & 63;
    f32x4 acc[2];
    acc[0] = (f32x4)0.f; acc[1] = (f32x4)0.f;
    const int arow = l & 15;
#pragma unroll
    for (int ks = 0; ks < 4; ++ks) {
        bf16x8 a = *(const bf16x8*)&sX[arow * LDX + ks * 32 + (l >> 4) * 8];
#pragma unroll
        for (int j = 0; j < 2; ++j) {
            const int nt = 2 * w + j;
            bf16x8 bb = *(const bf16x8*)&Bp[((size_t)(ks * 8 + nt) * 64 + l) * 8];
            acc[j] = __builtin_amdgcn_mfma_f32_16x16x32_bf16(a, bb, acc[j], 0, 0, 0);
        }
    }

    const int r0 = (l >> 4) * 4, cl = l & 15;
#pragma unroll
    for (int j = 0; j < 2; ++j) {
        const int col = (2 * w + j) * 16 + cl;
#pragma unroll
        for (int r = 0; r < 4; ++r)
            Y[(rb + r0 + r) * 128 + col] = f2bf(acc[j][r]);
    }
}

// XCD-aware swizzle for 2048 blocks: XCD k <- batches [8k,8k+8).
static __device__ __forceinline__ int swz_blk() {
    const int hw = blockIdx.x;
    return ((hw & 7) << 8) + (hw >> 3);
}

// ---------------------------------------------------------------------------
// k1: base = wordp + agg(libp, nbrL); t1 = tanh(base) (LDS only);
//     u = t1 @ enc2 (K=128 MFMA).  Writes baseh, u (bf16).
// ---------------------------------------------------------------------------
__global__ __launch_bounds__(256) void k1(const int* __restrict__ nbrL,
                                          const short* __restrict__ libp,
                                          const short* __restrict__ wordp,
                                          const short* __restrict__ Bp2,
                                          short* __restrict__ baseh,
                                          short* __restrict__ u) {
    __shared__ short sA[16 * LDX];
    __shared__ int sIdx[16 * 16];
    const int tid = threadIdx.x;
    const int blk = swz_blk();
    const int b = blk >> 5;
    const int node0 = blk * 16;

    if (tid < 64) *(int4*)&sIdx[tid * 4] = *(const int4*)&nbrL[(size_t)node0 * 16 + tid * 4];
    __syncthreads();

    const int w = tid >> 6, l = tid & 63;
    const int rh = l >> 5, c4 = l & 31;
    const short* libB = libp + (size_t)b * N_ * D_;

#pragma unroll
    for (int p = 0; p < 2; ++p) {
        const int row = 4 * w + 2 * p + rh;
        int idxr[16];
#pragma unroll
        for (int k = 0; k < 16; ++k) idxr[k] = sIdx[row * 16 + k];
        float s0 = 0.f, s1 = 0.f, s2 = 0.f, s3 = 0.f;
#pragma unroll
        for (int k = 0; k < 16; ++k) {
            uint2 uu = *(const uint2*)&libB[(size_t)idxr[k] * D_ + c4 * 4];
            s0 += bfbits2f(uu.x << 16); s1 += bfbits2f(uu.x & 0xffff0000u);
            s2 += bfbits2f(uu.y << 16); s3 += bfbits2f(uu.y & 0xffff0000u);
        }
        short4 wp = *(const short4*)&wordp[(size_t)(node0 + row) * D_ + c4 * 4];
        float b0 = bf2f(wp.x) + s0 * 0.0625f;
        float b1 = bf2f(wp.y) + s1 * 0.0625f;
        float b2 = bf2f(wp.z) + s2 * 0.0625f;
        float b3 = bf2f(wp.w) + s3 * 0.0625f;
        short4 bs; bs.x = f2bf(b0); bs.y = f2bf(b1); bs.z = f2bf(b2); bs.w = f2bf(b3);
        *(short4*)&baseh[(size_t)(node0 + row) * D_ + c4 * 4] = bs;
        short4 ts; ts.x = f2bf(fast_tanh(b0)); ts.y = f2bf(fast_tanh(b1));
        ts.z = f2bf(fast_tanh(b2)); ts.w = f2bf(fast_tanh(b3));
        *(short4*)&sA[row * LDX + c4 * 4] = ts;
    }
    __syncthreads();

    f32x4 acc[2];
    acc[0] = (f32x4)0.f; acc[1] = (f32x4)0.f;
    const int arow = l & 15;
#pragma unroll
    for (int ks = 0; ks < 4; ++ks) {
        bf16x8 a = *(const bf16x8*)&sA[arow * LDX + ks * 32 + (l >> 4) * 8];
#pragma unroll
        for (int j = 0; j < 2; ++j) {
            const int nt = 2 * w + j;
            bf16x8 bb = *(const bf16x8*)&Bp2[((size_t)(ks * 8 + nt) * 64 + l) * 8];
            acc[j] = __builtin_amdgcn_mfma_f32_16x16x32_bf16(a, bb, acc[j], 0, 0, 0);
        }
    }

    const int r0 = (l >> 4) * 4, cl = l & 15;
#pragma unroll
    for (int j = 0; j < 2; ++j) {
        const int col = (2 * w + j) * 16 + cl;
#pragma unroll
        for (int r = 0; r < 4; ++r)
            u[(size_t)(node0 + r0 + r) * D_ + col] = f2bf(acc[j][r]);
    }
}

// ---------------------------------------------------------------------------
// k2: t2 = tanh(base + agg(u, nbr)); out[b] += (sum_n mask*t2) @ w2
// No MFMA, no A-staging: pure gather + VALU.
// ---------------------------------------------------------------------------
__global__ __launch_bounds__(256) void k2(const int* __restrict__ nbr,
                                          const short* __restrict__ u,
                                          const short* __restrict__ baseh,
                                          const float* __restrict__ mask,
                                          const float* __restrict__ w2,
                                          float* __restrict__ out) {
    __shared__ int sIdx[16 * 16];
    __shared__ float smask[16];
    __shared__ float predp[8][128];
    __shared__ float pred[128];
    const int tid = threadIdx.x;
    const int blk = swz_blk();
    const int b = blk >> 5;
    const int node0 = blk * 16;

    if (tid < 64) *(int4*)&sIdx[tid * 4] = *(const int4*)&nbr[(size_t)node0 * 16 + tid * 4];
    if (tid >= 64 && tid < 80) smask[tid - 64] = mask[node0 + tid - 64];
    __syncthreads();

    const int w = tid >> 6, l = tid & 63;
    const int rh = l >> 5, c4 = l & 31;
    const short* uB = u + (size_t)b * N_ * D_;

    float a0 = 0.f, a1 = 0.f, a2c = 0.f, a3 = 0.f;
#pragma unroll
    for (int p = 0; p < 2; ++p) {
        const int row = 4 * w + 2 * p + rh;
        int idxr[16];
#pragma unroll
        for (int k = 0; k < 16; ++k) idxr[k] = sIdx[row * 16 + k];
        float s0 = 0.f, s1 = 0.f, s2 = 0.f, s3 = 0.f;
#pragma unroll
        for (int k = 0; k < 16; ++k) {
            uint2 uu = *(const uint2*)&uB[(size_t)idxr[k] * D_ + c4 * 4];
            s0 += bfbits2f(uu.x << 16); s1 += bfbits2f(uu.x & 0xffff0000u);
            s2 += bfbits2f(uu.y << 16); s3 += bfbits2f(uu.y & 0xffff0000u);
        }
        short4 bs = *(const short4*)&baseh[(size_t)(node0 + row) * D_ + c4 * 4];
        const float mk = smask[row];
        a0 += mk * fast_tanh(bf2f(bs.x) + s0 * 0.0625f);
        a1 += mk * fast_tanh(bf2f(bs.y) + s1 * 0.0625f);
        a2c += mk * fast_tanh(bf2f(bs.z) + s2 * 0.0625f);
        a3 += mk * fast_tanh(bf2f(bs.w) + s3 * 0.0625f);
    }
    const int pg = w * 2 + rh;
    predp[pg][c4 * 4 + 0] = a0;
    predp[pg][c4 * 4 + 1] = a1;
    predp[pg][c4 * 4 + 2] = a2c;
    predp[pg][c4 * 4 + 3] = a3;
    __syncthreads();

    if (tid < 128) {
        float tot = 0.f;
#pragma unroll
        for (int pgi = 0; pgi < 8; ++pgi) tot += predp[pgi][tid];
        pred[tid] = tot;
    }
    __syncthreads();
    if (tid < 128) {
        float acc = 0.f;
#pragma unroll 4
        for (int f = 0; f < 128; ++f) acc += pred[f] * w2[f * 128 + tid];
        atomicAdd(&out[b * 128 + tid], acc);
    }
}

extern "C" void kernel_launch(void* const* d_in, const int* in_sizes, int n_in,
                              void* d_out, int out_size, void* d_ws, size_t ws_size,
                              hipStream_t stream) {
    const float* word_embs   = (const float*)d_in[0];
    const int*   neibors     = (const int*)d_in[1];
    const float* lib_embs    = (const float*)d_in[2];
    const int*   neibors_lib = (const int*)d_in[3];
    const float* mask        = (const float*)d_in[4];
    const float* weight      = (const float*)d_in[5];
    const float* weight2     = (const float*)d_in[6];
    const float* enc_w1      = (const float*)d_in[7];
    const float* enc_w2      = (const float*)d_in[8];
    float* out = (float*)d_out;

    char* ws = (char*)d_ws;
    short* wordp = (short*)(ws);                       // 8 MB
    short* libp  = (short*)(ws + (1u << 23));          // 8 MB
    short* ubuf  = (short*)(ws + (2u << 23));          // 8 MB
    short* baseh = (short*)(ws + (3u << 23));          // 8 MB
    short* Bp1e  = (short*)(ws + (4u << 23));          // 32 KB
    short* Bpw   = (short*)(ws + (4u << 23) + 32768);  // 32 KB
    short* Bp2   = (short*)(ws + (4u << 23) + 65536);  // 32 KB

    pack<<<56, 256, 0, stream>>>(enc_w1, weight, enc_w2, Bp1e, Bpw, Bp2, out);
    proj<<<4096, 256, 0, stream>>>(word_embs, lib_embs, Bp1e, Bpw, wordp, libp);
    k1<<<2048, 256, 0, stream>>>(neibors_lib, libp, wordp, Bp2, baseh, ubuf);
    k2<<<2048, 256, 0, stream>>>(neibors, ubuf, baseh, mask, weight2, out);
}

// Round 10
// 53.469 us; speedup vs baseline: 1.0475x; 1.0475x over previous
//
#include <hip/hip_runtime.h>
#include <hip/hip_bf16.h>

#define B_   64
#define N_   512
#define K_   16
#define D_   128
#define NPB  16                 // nodes per block
#define G1   ((B_*N_)/NPB)      // 2048 blocks

typedef float f32x4  __attribute__((ext_vector_type(4)));
typedef short bf16x8 __attribute__((ext_vector_type(8)));

static __device__ __forceinline__ short f2bf(float x) {
    union { float f; unsigned u; } v; v.f = x;
    unsigned r = v.u + 0x7fffu + ((v.u >> 16) & 1u);  // RNE
    return (short)(r >> 16);
}
static __device__ __forceinline__ float bf2f(short h) {
    return __uint_as_float(((unsigned)(unsigned short)h) << 16);
}
// tanh(x) = 1 - 2/(e^{2x}+1); exact at +/-inf, ~1e-7 rel error
static __device__ __forceinline__ float fast_tanh(float x) {
    float e = __expf(2.f * x);
    return 1.f - 2.f * __builtin_amdgcn_rcpf(e + 1.f);
}
// packed 2xf32 add: acc += v in ONE VALU instruction (CDNA v_pk_add_f32)
static __device__ __forceinline__ void pk_add(float2& acc, float x, float y) {
    float2 v; v.x = x; v.y = y;
    asm("v_pk_add_f32 %0, %1, %0" : "+v"(acc) : "v"(v));
}

// ---------------------------------------------------------------------------
// pack: blocks 0..23 -> Bp1 (stacked [enc1;weight], K=256) + Bp2 (enc2, K=128)
//       blocks 24..55 -> zero d_out
// frag elem j of lane l, tile nt, step ks = B[ks*32 + (l>>4)*8 + j][nt*16 + (l&15)]
// ---------------------------------------------------------------------------
__global__ __launch_bounds__(256) void pack(const float* __restrict__ enc1,
                                            const float* __restrict__ wgt,
                                            const float* __restrict__ enc2,
                                            short* __restrict__ Bp1,
                                            short* __restrict__ Bp2,
                                            float* __restrict__ out) {
    const int blk = blockIdx.x, t = threadIdx.x;
    if (blk >= 24) { out[(blk - 24) * 256 + t] = 0.f; return; }
    int tid = blk * 256 + t;                 // 0..6143
    short o8[8];
    if (tid < 4096) {
        int l = tid & 63, nt = (tid >> 6) & 7, ks = tid >> 9;   // ks 0..7
        int k0 = ks * 32 + (l >> 4) * 8;
        int col = nt * 16 + (l & 15);
#pragma unroll
        for (int j = 0; j < 8; ++j) {
            int r = k0 + j;
            float v = (r < 128) ? enc1[r * 128 + col] : wgt[(r - 128) * 128 + col];
            o8[j] = f2bf(v);
        }
        *(int4*)&Bp1[(size_t)tid * 8] = *(int4*)o8;
    } else {
        int t2 = tid - 4096;
        int l = t2 & 63, nt = (t2 >> 6) & 7, ks = t2 >> 9;      // ks 0..3
        int k0 = ks * 32 + (l >> 4) * 8;
        int col = nt * 16 + (l & 15);
#pragma unroll
        for (int j = 0; j < 8; ++j) o8[j] = f2bf(enc2[(k0 + j) * 128 + col]);
        *(int4*)&Bp2[(size_t)t2 * 8] = *(int4*)o8;
    }
}

// XCD-aware swizzle: 2048 blocks, 32 per batch. XCD k (hw%8==k) gets logical
// blocks [256k,256k+256) = batches [8k,8k+8) -> per-XCD L2 working set ~3 MB.
static __device__ __forceinline__ int swz_blk() {
    const int hw = blockIdx.x;
    return ((hw & 7) << 8) + (hw >> 3);
}

#define LDA1 264   // 256 + 8 pad shorts
#define LDA2 136   // 128 + 8 pad shorts

// ---------------------------------------------------------------------------
// gemm1: base = [word | agg(lib,nbrL)] @ [enc1;weight] (K=256); t1 = tanh(base)
// fp32 gather + v_pk_add_f32 accumulation (0.75 VALU/elem vs 2 for bf16 unpack).
// baseh stored bf16; t1 stored fp32 (so gemm2's gather is also pk_add).
// ---------------------------------------------------------------------------
__global__ __launch_bounds__(256) void gemm1(const float* __restrict__ word,
                                             const int* __restrict__ nbrL,
                                             const float* __restrict__ lib,
                                             const short* __restrict__ Bp1,
                                             short* __restrict__ baseh,
                                             float* __restrict__ t1f) {
    __shared__ short sA[NPB * LDA1];
    __shared__ int sIdx[NPB * 16];
    const int tid = threadIdx.x;
    const int blk = swz_blk();
    const int b = blk >> 5;
    const int node0 = blk * NPB;

    if (tid < 64) *(int4*)&sIdx[tid * 4] = *(const int4*)&nbrL[(size_t)node0 * 16 + tid * 4];
    __syncthreads();

    const int w = tid >> 6, l = tid & 63;
    const int rh = l >> 5, c4 = l & 31;         // row-half, 4-col group
    const float* libB = lib + (size_t)b * N_ * D_;

#pragma unroll
    for (int p = 0; p < 2; ++p) {
        const int row = 4 * w + 2 * p + rh;
        const int gid = node0 + row;
        float4 wv = *(const float4*)&word[(size_t)gid * D_ + c4 * 4];
        short4 ws; ws.x = f2bf(wv.x); ws.y = f2bf(wv.y); ws.z = f2bf(wv.z); ws.w = f2bf(wv.w);
        *(short4*)&sA[row * LDA1 + c4 * 4] = ws;
        int idxr[16];
#pragma unroll
        for (int q = 0; q < 4; ++q) *(int4*)&idxr[q * 4] = *(const int4*)&sIdx[row * 16 + q * 4];
        float2 a01 = {0.f, 0.f}, a23 = {0.f, 0.f};
#pragma unroll
        for (int k = 0; k < 16; ++k) {
            float4 lv = *(const float4*)&libB[(size_t)idxr[k] * D_ + c4 * 4];
            pk_add(a01, lv.x, lv.y);
            pk_add(a23, lv.z, lv.w);
        }
        short4 as; as.x = f2bf(a01.x * 0.0625f); as.y = f2bf(a01.y * 0.0625f);
        as.z = f2bf(a23.x * 0.0625f); as.w = f2bf(a23.y * 0.0625f);
        *(short4*)&sA[row * LDA1 + 128 + c4 * 4] = as;
    }
    __syncthreads();

    f32x4 acc[2];
    acc[0] = (f32x4)0.f; acc[1] = (f32x4)0.f;
    const int arow = l & 15;
#pragma unroll
    for (int ks = 0; ks < 8; ++ks) {
        bf16x8 a = *(const bf16x8*)&sA[arow * LDA1 + ks * 32 + (l >> 4) * 8];
#pragma unroll
        for (int j = 0; j < 2; ++j) {
            const int nt = 2 * w + j;
            bf16x8 bb = *(const bf16x8*)&Bp1[((size_t)(ks * 8 + nt) * 64 + l) * 8];
            acc[j] = __builtin_amdgcn_mfma_f32_16x16x32_bf16(a, bb, acc[j], 0, 0, 0);
        }
    }

    const int r0 = (l >> 4) * 4;
    const int cl = l & 15;
#pragma unroll
    for (int j = 0; j < 2; ++j) {
        const int col = (2 * w + j) * 16 + cl;
#pragma unroll
        for (int r = 0; r < 4; ++r) {
            size_t o = (size_t)(node0 + r0 + r) * D_ + col;
            float v = acc[j][r];
            baseh[o] = f2bf(v);
            t1f[o]   = fast_tanh(v);
        }
    }
}

// ---------------------------------------------------------------------------
// gemm2: t2 = tanh(base + agg(t1,nbr) @ enc2);
//        out[b] += (sum_n mask*t2) @ weight2   (atomic into d_out)
// fp32 t1 gather with pk_add.
// ---------------------------------------------------------------------------
__global__ __launch_bounds__(256) void gemm2(const float* __restrict__ t1f,
                                             const int* __restrict__ nbr,
                                             const short* __restrict__ Bp2,
                                             const short* __restrict__ baseh,
                                             const float* __restrict__ mask,
                                             const float* __restrict__ w2,
                                             float* __restrict__ out) {
    __shared__ short sA[NPB * LDA2];
    __shared__ int sIdx[NPB * 16];
    __shared__ float pred[128];
    __shared__ float smask[NPB];
    const int tid = threadIdx.x;
    const int blk = swz_blk();
    const int b = blk >> 5;
    const int node0 = blk * NPB;

    if (tid < 64) *(int4*)&sIdx[tid * 4] = *(const int4*)&nbr[(size_t)node0 * 16 + tid * 4];
    if (tid >= 64 && tid < 64 + NPB) smask[tid - 64] = mask[node0 + tid - 64];
    __syncthreads();

    const int w = tid >> 6, l = tid & 63;
    const int rh = l >> 5, c4 = l & 31;
    const float* t1B = t1f + (size_t)b * N_ * D_;

#pragma unroll
    for (int p = 0; p < 2; ++p) {
        const int row = 4 * w + 2 * p + rh;
        int idxr[16];
#pragma unroll
        for (int q = 0; q < 4; ++q) *(int4*)&idxr[q * 4] = *(const int4*)&sIdx[row * 16 + q * 4];
        float2 a01 = {0.f, 0.f}, a23 = {0.f, 0.f};
#pragma unroll
        for (int k = 0; k < 16; ++k) {
            float4 lv = *(const float4*)&t1B[(size_t)idxr[k] * D_ + c4 * 4];
            pk_add(a01, lv.x, lv.y);
            pk_add(a23, lv.z, lv.w);
        }
        short4 as; as.x = f2bf(a01.x * 0.0625f); as.y = f2bf(a01.y * 0.0625f);
        as.z = f2bf(a23.x * 0.0625f); as.w = f2bf(a23.y * 0.0625f);
        *(short4*)&sA[row * LDA2 + c4 * 4] = as;
    }
    __syncthreads();

    f32x4 acc[2];
    acc[0] = (f32x4)0.f; acc[1] = (f32x4)0.f;
    const int arow = l & 15;
#pragma unroll
    for (int ks = 0; ks < 4; ++ks) {
        bf16x8 a = *(const bf16x8*)&sA[arow * LDA2 + ks * 32 + (l >> 4) * 8];
#pragma unroll
        for (int j = 0; j < 2; ++j) {
            const int nt = 2 * w + j;
            bf16x8 bb = *(const bf16x8*)&Bp2[((size_t)(ks * 8 + nt) * 64 + l) * 8];
            acc[j] = __builtin_amdgcn_mfma_f32_16x16x32_bf16(a, bb, acc[j], 0, 0, 0);
        }
    }

    const int r0 = (l >> 4) * 4;
    const int cl = l & 15;
#pragma unroll
    for (int j = 0; j < 2; ++j) {
        const int col = (2 * w + j) * 16 + cl;
        float s = 0.f;
#pragma unroll
        for (int r = 0; r < 4; ++r) {
            size_t o = (size_t)(node0 + r0 + r) * D_ + col;
            float v = fast_tanh(bf2f(baseh[o]) + acc[j][r]);
            s += v * smask[r0 + r];
        }
        s += __shfl_xor(s, 16);
        s += __shfl_xor(s, 32);
        if (l < 16) pred[col] = s;
    }
    __syncthreads();
    if (tid < 128) {
        float a2 = 0.f;
#pragma unroll 4
        for (int f = 0; f < 128; ++f) a2 += pred[f] * w2[f * 128 + tid];
        atomicAdd(&out[b * 128 + tid], a2);
    }
}

extern "C" void kernel_launch(void* const* d_in, const int* in_sizes, int n_in,
                              void* d_out, int out_size, void* d_ws, size_t ws_size,
                              hipStream_t stream) {
    const float* word_embs   = (const float*)d_in[0];
    const int*   neibors     = (const int*)d_in[1];
    const float* lib_embs    = (const float*)d_in[2];
    const int*   neibors_lib = (const int*)d_in[3];
    const float* mask        = (const float*)d_in[4];
    const float* weight      = (const float*)d_in[5];
    const float* weight2     = (const float*)d_in[6];
    const float* enc_w1      = (const float*)d_in[7];
    const float* enc_w2      = (const float*)d_in[8];
    float* out = (float*)d_out;

    char* ws = (char*)d_ws;
    short* baseh = (short*)(ws);                        // 8 MB
    float* t1f   = (float*)(ws + (1u << 23));           // 16 MB
    short* Bp1   = (short*)(ws + (3u << 23));           // 64 KB
    short* Bp2   = (short*)(ws + (3u << 23) + 65536);   // 32 KB

    pack<<<56, 256, 0, stream>>>(enc_w1, weight, enc_w2, Bp1, Bp2, out);
    gemm1<<<G1, 256, 0, stream>>>(word_embs, neibors_lib, lib_embs, Bp1, baseh, t1f);
    gemm2<<<G1, 256, 0, stream>>>(t1f, neibors, Bp2, baseh, mask, weight2, out);
}